// Round 1
// 218.660 us; speedup vs baseline: 1.0535x; 1.0535x over previous
//
#include <hip/hip_runtime.h>
#include <math.h>

#define DIN 1024
#define DH 512
#define DATT 256
#define CNUM 10
#define NCLS 4
#define NH 64              // histogram blocks (fallback path)
#define NSC 40             // scatter blocks

typedef __attribute__((ext_vector_type(8))) short bf16x8;
typedef __attribute__((ext_vector_type(4))) float f32x4;
typedef unsigned short ushort_t;
typedef unsigned int uint_t;

__device__ inline ushort_t f2bf(float f) {
    uint_t u = __float_as_uint(f);
    u += 0x7FFF + ((u >> 16) & 1);   // RNE
    return (ushort_t)(u >> 16);
}

// async global->LDS, 16B per lane. LDS dst must be wave-uniform base + lane*16.
__device__ inline void gl_lds16(const void* g, void* l) {
    __builtin_amdgcn_global_load_lds(
        (const __attribute__((address_space(1))) unsigned int*)g,
        (__attribute__((address_space(3))) unsigned int*)l, 16, 0, 0);
}

// ============================ FAST PATH ============================
// dispatch 1: memset (pooled + scat_pos, 20.5 KB)
// dispatch 2: k_prep  = a_logit init | direct-atomic scatter | x cast | W transpose+cast
// dispatch 3: k_g1    = grouped GEMM1 (BK=64 dbuf, counted vmcnt, swizzled LDS)
// dispatch 4: k_g2    = grouped GEMM2 + relu colsum -> pooled
// dispatch 5-7: k_fc2 / k_gate2 / k_final (unchanged tail)

__global__ __launch_bounds__(256) void k_prep(
    const int* __restrict__ cid, int n, const float* __restrict__ bc,
    const float* __restrict__ x, const float* __restrict__ W1, const float* __restrict__ W2,
    ushort_t* __restrict__ xb, ushort_t* __restrict__ W1t, ushort_t* __restrict__ W2t,
    int nxb, int nw,
    float* __restrict__ a_logit, int* __restrict__ scat_pos, int* __restrict__ bucket)
{
    int bid = blockIdx.x;
    int t = threadIdx.x;

    if (bid == 0) {                       // init block
        if (t < CNUM) a_logit[t] = bc[0];
        return;
    }
    bid -= 1;

    if (bid < NSC) {                      // direct-atomic scatter into padded buckets
        int lane = t & 63;
        for (int i = bid * 256 + t; i < n; i += NSC * 256) {
            int c = cid[i];
            #pragma unroll
            for (int cc = 0; cc < CNUM; cc++) {
                unsigned long long mask = __ballot(c == cc);
                if (mask == 0ull) continue;
                int leader = __ffsll(mask) - 1;
                int basep = 0;
                if (lane == leader) basep = atomicAdd(&scat_pos[cc], __popcll(mask));
                basep = __shfl(basep, leader, 64);
                if (c == cc) {
                    int rank = __popcll(mask & ((1ull << lane) - 1ull));
                    bucket[cc * n + basep + rank] = i;
                }
            }
        }
        return;
    }
    bid -= NSC;

    if (bid < nxb) {                      // cast x fp32 -> bf16, 4 rows/block
        int row = bid * 4 + (t >> 6);
        if (row >= n) return;
        int col = (t & 63) * 16;
        const float* src = x + (size_t)row * DIN + col;
        ushort_t* dst = xb + (size_t)row * DIN + col;
        #pragma unroll
        for (int j = 0; j < 4; j++) {
            float4 v = *(const float4*)(src + 4 * j);
            *(ushort4*)(dst + 4 * j) = make_ushort4(f2bf(v.x), f2bf(v.y), f2bf(v.z), f2bf(v.w));
        }
        return;
    }
    bid -= nxb;

    if (bid < nw) {                       // transpose+cast W1,W2 -> n-major bf16
        __shared__ float tile[64][65];
        int z = bid >> 7;
        int kx = (bid & 127) >> 3;
        int ny = bid & 7;
        const float* src; ushort_t* dst; int K;
        if (z < CNUM) { K = DIN; src = W1 + (size_t)z * K * DH; dst = W1t + (size_t)z * DH * K; }
        else          { K = DH;  src = W2 + (size_t)(z - CNUM) * K * DH; dst = W2t + (size_t)(z - CNUM) * DH * K; }
        int k0 = kx * 64;
        if (k0 >= K) return;
        int n0 = ny * 64;
        int rr = t >> 4;
        int cc = (t & 15) * 4;
        #pragma unroll
        for (int i = 0; i < 4; i++) {
            int row = rr + 16 * i;
            float4 v = *(const float4*)(src + (size_t)(k0 + row) * DH + n0 + cc);
            tile[row][cc + 0] = v.x; tile[row][cc + 1] = v.y;
            tile[row][cc + 2] = v.z; tile[row][cc + 3] = v.w;
        }
        __syncthreads();
        #pragma unroll
        for (int i = 0; i < 4; i++) {
            int nrow = rr + 16 * i;
            ushort4 o = make_ushort4(f2bf(tile[cc + 0][nrow]), f2bf(tile[cc + 1][nrow]),
                                     f2bf(tile[cc + 2][nrow]), f2bf(tile[cc + 3][nrow]));
            *(ushort4*)(dst + (size_t)(n0 + nrow) * K + k0 + cc) = o;
        }
    }
}

// ------- BK=64 double-buffered pipeline core (T3-min + T4 + T2 swizzle) -------
// LDS tile [128][64] bf16 per operand, 2 buffers = 64 KB total.
// XOR chunk swizzle: 16B-chunk index ^= (row&7), applied on the GLOBAL source
// address (gl_lds dest must stay linear) and identically on the ds_read side.

__device__ inline void stage8(
    const ushort_t* a0, const ushort_t* a1, const ushort_t* a2, const ushort_t* a3,
    const ushort_t* b0, const ushort_t* b1, const ushort_t* b2, const ushort_t* b3,
    int ko, ushort_t* As, ushort_t* Bs, int t)
{
    gl_lds16(a0 + ko, As + 0 * 2048 + t * 8);
    gl_lds16(a1 + ko, As + 1 * 2048 + t * 8);
    gl_lds16(a2 + ko, As + 2 * 2048 + t * 8);
    gl_lds16(a3 + ko, As + 3 * 2048 + t * 8);
    gl_lds16(b0 + ko, Bs + 0 * 2048 + t * 8);
    gl_lds16(b1 + ko, Bs + 1 * 2048 + t * 8);
    gl_lds16(b2 + ko, Bs + 2 * 2048 + t * 8);
    gl_lds16(b3 + ko, Bs + 3 * 2048 + t * 8);
}

__device__ inline void mfma_tile(const ushort_t* As, const ushort_t* Bs,
                                 f32x4 (&acc)[4][4], int wr, int wc, int m, int quad)
{
    bf16x8 a[2][4], b[2][4];
    #pragma unroll
    for (int ks = 0; ks < 2; ks++) {
        int chunk = ((ks * 4 + quad) ^ (m & 7)) * 8;      // row&7 == m&7 for all frag rows
        #pragma unroll
        for (int mf = 0; mf < 4; mf++)
            a[ks][mf] = *(const bf16x8*)(As + (64 * wr + 16 * mf + m) * 64 + chunk);
        #pragma unroll
        for (int nf = 0; nf < 4; nf++)
            b[ks][nf] = *(const bf16x8*)(Bs + (64 * wc + 16 * nf + m) * 64 + chunk);
    }
    // reads must COMPLETE before next stage overwrites this buffer (anti-dep the
    // compiler cannot see) -> explicit lgkmcnt(0) before the consume-barrier.
    asm volatile("s_waitcnt lgkmcnt(0)" ::: "memory");
    __builtin_amdgcn_sched_barrier(0);
    __builtin_amdgcn_s_barrier();
    __builtin_amdgcn_sched_barrier(0);
    #pragma unroll
    for (int ks = 0; ks < 2; ks++)
        #pragma unroll
        for (int mf = 0; mf < 4; mf++)
            #pragma unroll
            for (int nf = 0; nf < 4; nf++)
                acc[mf][nf] = __builtin_amdgcn_mfma_f32_16x16x32_bf16(a[ks][mf], b[ks][nf], acc[mf][nf], 0, 0, 0);
}

__device__ inline void gemm_loop(
    const ushort_t* a0, const ushort_t* a1, const ushort_t* a2, const ushort_t* a3,
    const ushort_t* b0, const ushort_t* b1, const ushort_t* b2, const ushort_t* b3,
    int KT, f32x4 (&acc)[4][4], ushort_t* As, ushort_t* Bs)
{
    int t = threadIdx.x;
    int lane = t & 63;
    int w = t >> 6, wr = w >> 1, wc = w & 1;
    int m = lane & 15, quad = lane >> 4;

    stage8(a0, a1, a2, a3, b0, b1, b2, b3, 0, As, Bs, t);       // tile 0 -> buf0
    for (int kt = 0; kt < KT; kt += 2) {
        // ---- compute buf0 (tile kt) while staging tile kt+1 -> buf1 ----
        stage8(a0, a1, a2, a3, b0, b1, b2, b3, (kt + 1) * 64, As + 8192, Bs + 8192, t);
        asm volatile("s_waitcnt vmcnt(8)" ::: "memory");        // tile kt resident
        __builtin_amdgcn_sched_barrier(0);
        __builtin_amdgcn_s_barrier();
        __builtin_amdgcn_sched_barrier(0);
        mfma_tile(As, Bs, acc, wr, wc, m, quad);

        // ---- compute buf1 (tile kt+1) while staging tile kt+2 -> buf0 ----
        if (kt + 2 < KT) {
            stage8(a0, a1, a2, a3, b0, b1, b2, b3, (kt + 2) * 64, As, Bs, t);
            asm volatile("s_waitcnt vmcnt(8)" ::: "memory");
        } else {
            asm volatile("s_waitcnt vmcnt(0)" ::: "memory");
        }
        __builtin_amdgcn_sched_barrier(0);
        __builtin_amdgcn_s_barrier();
        __builtin_amdgcn_sched_barrier(0);
        mfma_tile(As + 8192, Bs + 8192, acc, wr, wc, m, quad);
    }
}

// tile mapping: bijective XCD remap (T1) then counts-prefix -> (cluster, m0)
__device__ inline int tile_decode(int bid, int MAXT, const int* counts,
                                  int& c, int& m0, int& tile_n)
{
    int mt, nt;
    if ((MAXT & 7) == 0) {
        int mtpx = MAXT >> 3;
        int xcd = bid & 7, j = bid >> 3;
        nt = j / mtpx;                       // B-panel-major within an XCD chunk
        mt = xcd * mtpx + (j - nt * mtpx);
    } else { mt = bid >> 2; nt = bid & 3; }

    int rem = mt;
    c = 0;
    #pragma unroll
    for (int cc = 0; cc < CNUM; cc++) {
        int tc = (counts[cc] + 127) >> 7;
        if (rem < tc) { c = cc; m0 = rem * 128; tile_n = nt * 128; return 1; }
        rem -= tc;
    }
    return 0;
}

__global__ __launch_bounds__(256) void k_g1(
    const ushort_t* __restrict__ xb, const ushort_t* __restrict__ W1t,
    const float* __restrict__ b1, const int* __restrict__ bucket,
    const int* __restrict__ counts, int n, int MAXT,
    ushort_t* __restrict__ H1)
{
    __shared__ ushort_t As[2][128][64];
    __shared__ ushort_t Bs[2][128][64];

    int c, m0, tile_n;
    if (!tile_decode(blockIdx.x, MAXT, counts, c, m0, tile_n)) return;
    int cnt = counts[c];

    int t = threadIdx.x;
    int rr = t >> 3;                                   // row within 32-row site
    int swz = ((t & 7) ^ (rr & 7)) * 8;                // pre-swizzled global chunk

    const ushort_t* aP[4];
    const ushort_t* bP[4];
    #pragma unroll
    for (int s = 0; s < 4; s++) {
        int ra = m0 + s * 32 + rr;
        if (ra > cnt - 1) ra = cnt - 1;
        aP[s] = xb + (size_t)bucket[c * n + ra] * DIN + swz;            // indirect gather
        bP[s] = W1t + ((size_t)c * DH + tile_n + s * 32 + rr) * DIN + swz;
    }

    f32x4 acc[4][4] = {};
    gemm_loop(aP[0], aP[1], aP[2], aP[3], bP[0], bP[1], bP[2], bP[3],
              DIN / 64, acc, &As[0][0][0], &Bs[0][0][0]);

    int lane = t & 63;
    int w = t >> 6, wr = w >> 1, wc = w & 1;
    int m = lane & 15, quad = lane >> 4;
    int col0 = tile_n + 64 * wc;
    #pragma unroll
    for (int nf = 0; nf < 4; nf++) {
        int col = col0 + 16 * nf + m;
        float bv = b1[c * DH + col];
        #pragma unroll
        for (int mf = 0; mf < 4; mf++) {
            int rowb = m0 + 64 * wr + 16 * mf + quad * 4;
            #pragma unroll
            for (int r = 0; r < 4; r++) {
                int row = rowb + r;
                if (row < cnt)
                    H1[((size_t)c * n + row) * DH + col] = f2bf(fmaxf(acc[mf][nf][r] + bv, 0.f));
            }
        }
    }
}

__global__ __launch_bounds__(256) void k_g2(
    const ushort_t* __restrict__ H1, const ushort_t* __restrict__ W2t,
    const float* __restrict__ b2, const int* __restrict__ counts, int n, int MAXT,
    float* __restrict__ pooled)
{
    __shared__ ushort_t As[2][128][64];
    __shared__ ushort_t Bs[2][128][64];

    int c, m0, tile_n;
    if (!tile_decode(blockIdx.x, MAXT, counts, c, m0, tile_n)) return;
    int cnt = counts[c];

    int t = threadIdx.x;
    int rr = t >> 3;
    int swz = ((t & 7) ^ (rr & 7)) * 8;

    const ushort_t* aP[4];
    const ushort_t* bP[4];
    #pragma unroll
    for (int s = 0; s < 4; s++) {
        int ra = m0 + s * 32 + rr;
        if (ra > cnt - 1) ra = cnt - 1;
        aP[s] = H1 + ((size_t)c * n + ra) * DH + swz;
        bP[s] = W2t + ((size_t)c * DH + tile_n + s * 32 + rr) * DH + swz;
    }

    f32x4 acc[4][4] = {};
    gemm_loop(aP[0], aP[1], aP[2], aP[3], bP[0], bP[1], bP[2], bP[3],
              DH / 64, acc, &As[0][0][0], &Bs[0][0][0]);

    int lane = t & 63;
    int w = t >> 6, wr = w >> 1, wc = w & 1;
    int m = lane & 15, quad = lane >> 4;
    int col0 = tile_n + 64 * wc;
    #pragma unroll
    for (int nf = 0; nf < 4; nf++) {
        int col = col0 + 16 * nf + m;
        float bv = b2[c * DH + col];
        float s = 0.f;
        #pragma unroll
        for (int mf = 0; mf < 4; mf++) {
            int rowb = m0 + 64 * wr + 16 * mf + quad * 4;
            #pragma unroll
            for (int r = 0; r < 4; r++) {
                int row = rowb + r;
                if (row < cnt) s += fmaxf(acc[mf][nf][r] + bv, 0.f);
            }
        }
        s += __shfl_xor(s, 16);
        s += __shfl_xor(s, 32);
        if (quad == 0) atomicAdd(&pooled[c * DH + col], s);
    }
}

// ---------------- parallel epilogue (unchanged, proven) ----------------

__global__ __launch_bounds__(256) void k_fc2(
    const float* __restrict__ pooled, const int* __restrict__ counts,
    const float* __restrict__ Wfc, const float* __restrict__ bfc,
    float* __restrict__ hfc)
{
    int c = blockIdx.x;
    int c0 = blockIdx.y * 64;
    __shared__ float ps[DH];
    __shared__ float red[4][64];
    int t = threadIdx.x;
    float cnt = fmaxf((float)counts[c], 1.f);
    ps[t] = pooled[c * DH + t] / cnt;
    ps[t + 256] = pooled[c * DH + t + 256] / cnt;
    __syncthreads();
    int col = c0 + (t & 63);
    int ks = t >> 6;
    float acc = 0.f;
    #pragma unroll 8
    for (int k = ks * 128; k < ks * 128 + 128; k++)
        acc = fmaf(ps[k], Wfc[(size_t)k * DH + col], acc);
    red[ks][t & 63] = acc;
    __syncthreads();
    if (t < 64) {
        float v = red[0][t] + red[1][t] + red[2][t] + red[3][t] + bfc[c0 + t];
        hfc[c * DH + c0 + t] = fmaxf(v, 0.f);
    }
}

__global__ __launch_bounds__(256) void k_gate2(
    const float* __restrict__ hfc,
    const float* __restrict__ Wa, const float* __restrict__ ba,
    const float* __restrict__ Wb, const float* __restrict__ bb,
    const float* __restrict__ Wc,
    float* __restrict__ a_logit)
{
    int c = blockIdx.x;
    int d0 = blockIdx.y * 64;
    __shared__ float hf[DH];
    __shared__ float ra[4][64], rb[4][64];
    int t = threadIdx.x;
    hf[t] = hfc[c * DH + t];
    hf[t + 256] = hfc[c * DH + t + 256];
    __syncthreads();
    int d = d0 + (t & 63);
    int ks = t >> 6;
    float ga = 0.f, gb = 0.f;
    #pragma unroll 8
    for (int k = ks * 128; k < ks * 128 + 128; k++) {
        float h = hf[k];
        ga = fmaf(h, Wa[(size_t)k * DATT + d], ga);
        gb = fmaf(h, Wb[(size_t)k * DATT + d], gb);
    }
    ra[ks][t & 63] = ga;
    rb[ks][t & 63] = gb;
    __syncthreads();
    if (t < 64) {
        float sa = ra[0][t] + ra[1][t] + ra[2][t] + ra[3][t] + ba[d0 + t];
        float sb = rb[0][t] + rb[1][t] + rb[2][t] + rb[3][t] + bb[d0 + t];
        float g = tanhf(sa) * (1.f / (1.f + expf(-sb)));
        float p = g * Wc[d0 + t];
        #pragma unroll
        for (int off = 32; off >= 1; off >>= 1) p += __shfl_down(p, off, 64);
        if (t == 0) atomicAdd(&a_logit[c], p);
    }
}

__global__ __launch_bounds__(1024) void k_final(
    const float* __restrict__ hfc, const float* __restrict__ a_logit,
    const float* __restrict__ Wr, const float* __restrict__ br,
    const float* __restrict__ Wcls, const float* __restrict__ bcls,
    float* __restrict__ out)
{
    int t = threadIdx.x;
    __shared__ float hp[DH];
    __shared__ float r1[4][DATT];
    __shared__ float hr[DATT];
    __shared__ float wred[4][NCLS];

    float al[CNUM];
    float m = -1e30f;
    #pragma unroll
    for (int c = 0; c < CNUM; c++) { al[c] = a_logit[c]; m = fmaxf(m, al[c]); }
    float s = 0.f;
    #pragma unroll
    for (int c = 0; c < CNUM; c++) { al[c] = expf(al[c] - m); s += al[c]; }
    float inv = 1.f / s;

    if (t < DH) {
        float v = 0.f;
        #pragma unroll
        for (int c = 0; c < CNUM; c++) v = fmaf(al[c] * inv, hfc[c * DH + t], v);
        hp[t] = v;
    }
    __syncthreads();

    int d = t & 255;
    int ks = t >> 8;
    float acc = 0.f;
    #pragma unroll 8
    for (int k = ks * 128; k < ks * 128 + 128; k++)
        acc = fmaf(hp[k], Wr[(size_t)k * DATT + d], acc);
    r1[ks][d] = acc;
    __syncthreads();
    if (t < DATT)
        hr[t] = fmaxf(r1[0][t] + r1[1][t] + r1[2][t] + r1[3][t] + br[t], 0.f);
    __syncthreads();

    if (t < 256) {
        float h = hr[t];
        #pragma unroll
        for (int cls = 0; cls < NCLS; cls++) {
            float p = h * Wcls[(size_t)t * NCLS + cls];
            #pragma unroll
            for (int off = 32; off >= 1; off >>= 1) p += __shfl_down(p, off, 64);
            if ((t & 63) == 0) wred[t >> 6][cls] = p;
        }
    }
    __syncthreads();
    if (t == 0) {
        float lg[NCLS];
        #pragma unroll
        for (int cls = 0; cls < NCLS; cls++)
            lg[cls] = bcls[cls] + wred[0][cls] + wred[1][cls] + wred[2][cls] + wred[3][cls];
        float mm = lg[0];
        #pragma unroll
        for (int i = 1; i < NCLS; i++) mm = fmaxf(mm, lg[i]);
        float ss = 0.f, pr[NCLS];
        #pragma unroll
        for (int i = 0; i < NCLS; i++) { pr[i] = expf(lg[i] - mm); ss += pr[i]; }
        int am = 0; float best = lg[0];
        #pragma unroll
        for (int i = 1; i < NCLS; i++) if (lg[i] > best) { best = lg[i]; am = i; }
        #pragma unroll
        for (int i = 0; i < NCLS; i++) out[i] = lg[i];
        #pragma unroll
        for (int i = 0; i < NCLS; i++) out[4 + i] = pr[i] / ss;
        out[8] = (float)am;
    }
}

// ==================== FALLBACK PATH (small ws) — unchanged ====================

__global__ __launch_bounds__(256) void k_hist(
    const int* __restrict__ cid, int n, const float* __restrict__ bc,
    int* __restrict__ counts_part, float* __restrict__ pooled,
    float* __restrict__ a_logit, int* __restrict__ scat_pos)
{
    int bid = blockIdx.x;
    int t = threadIdx.x;

    if (bid < NH) {
        __shared__ int h[CNUM];
        int lane = t & 63;
        if (t < CNUM) h[t] = 0;
        __syncthreads();
        for (int i = bid * 256 + t; i < n; i += NH * 256) {
            int c = cid[i];
            #pragma unroll
            for (int cc = 0; cc < CNUM; cc++) {
                unsigned long long mask = __ballot(c == cc);
                if (mask == 0ull) continue;
                if (lane == (__ffsll(mask) - 1)) atomicAdd(&h[cc], __popcll(mask));
            }
        }
        __syncthreads();
        if (t < CNUM) counts_part[bid * 16 + t] = h[t];
        return;
    }

    for (int i = t; i < CNUM * DH; i += 256) pooled[i] = 0.f;
    if (t < CNUM) a_logit[t] = bc[0];
    if (t < CNUM) scat_pos[t] = 0;
}

__global__ __launch_bounds__(256) void k_scat_fb(
    const int* __restrict__ cid, int n, const int* __restrict__ counts_part,
    int* __restrict__ counts, int* __restrict__ offsets,
    int* __restrict__ scat_pos, int* __restrict__ bucket)
{
    int bid = blockIdx.x;
    int t = threadIdx.x;
    __shared__ int cnts[CNUM], off[CNUM];
    if (t < CNUM) {
        int s = 0;
        #pragma unroll 8
        for (int b = 0; b < NH; b++) s += counts_part[b * 16 + t];
        cnts[t] = s;
    }
    __syncthreads();
    if (t == 0) {
        int a = 0;
        for (int c = 0; c < CNUM; c++) { off[c] = a; a += cnts[c]; }
        if (bid == 0) {
            int aa = 0;
            for (int c = 0; c < CNUM; c++) { offsets[c] = aa; counts[c] = cnts[c]; aa += cnts[c]; }
            offsets[CNUM] = aa;
        }
    }
    __syncthreads();
    int lane = t & 63;
    for (int i = bid * 256 + t; i < n; i += NSC * 256) {
        int c = cid[i];
        #pragma unroll
        for (int cc = 0; cc < CNUM; cc++) {
            unsigned long long mask = __ballot(c == cc);
            if (mask == 0ull) continue;
            int leader = __ffsll(mask) - 1;
            int basep = 0;
            if (lane == leader) basep = atomicAdd(&scat_pos[cc], __popcll(mask));
            basep = __shfl(basep, leader, 64);
            if (c == cc) {
                int rank = __popcll(mask & ((1ull << lane) - 1ull));
                bucket[off[cc] + basep + rank] = i;
            }
        }
    }
}

#define MT 64
#define NT 128
#define KT 32

__global__ __launch_bounds__(256) void k_gemm1(
    const float* __restrict__ x, const float* __restrict__ W1, const float* __restrict__ b1,
    const int* __restrict__ bucket, const int* __restrict__ offsets, const int* __restrict__ counts,
    float* __restrict__ H1)
{
    int c = blockIdx.z;
    int cnt = counts[c];
    int m0 = blockIdx.x * MT;
    if (m0 >= cnt) return;
    int rows = min(MT, cnt - m0);
    int n0 = blockIdx.y * NT;
    int base = offsets[c];

    __shared__ float As[KT][MT + 4];
    __shared__ float Bs[KT][NT];

    int t = threadIdx.x;
    int tr = t >> 4;
    int tc = t & 15;
    int lr = t >> 2;
    int lk = (t & 3) * 8;
    const float* xrow = nullptr;
    if (lr < rows) xrow = x + (size_t)bucket[base + m0 + lr] * DIN;

    float acc[4][8];
    #pragma unroll
    for (int i = 0; i < 4; i++)
        #pragma unroll
        for (int j = 0; j < 8; j++) acc[i][j] = 0.f;

    const float* Wp = W1 + (size_t)c * DIN * DH + n0;

    for (int k0 = 0; k0 < DIN; k0 += KT) {
        __syncthreads();
        if (xrow) {
            float4 v0 = *(const float4*)(xrow + k0 + lk);
            float4 v1 = *(const float4*)(xrow + k0 + lk + 4);
            As[lk + 0][lr] = v0.x; As[lk + 1][lr] = v0.y;
            As[lk + 2][lr] = v0.z; As[lk + 3][lr] = v0.w;
            As[lk + 4][lr] = v1.x; As[lk + 5][lr] = v1.y;
            As[lk + 6][lr] = v1.z; As[lk + 7][lr] = v1.w;
        } else {
            #pragma unroll
            for (int i = 0; i < 8; i++) As[lk + i][lr] = 0.f;
        }
        #pragma unroll
        for (int i = 0; i < 4; i++) {
            int idx = i * 256 + t;
            int kk = idx >> 5;
            int cv = idx & 31;
            *(float4*)&Bs[kk][cv * 4] = *(const float4*)(Wp + (size_t)(k0 + kk) * DH + cv * 4);
        }
        __syncthreads();
        #pragma unroll
        for (int k = 0; k < KT; k++) {
            float4 av  = *(const float4*)&As[k][4 * tr];
            float4 bv0 = *(const float4*)&Bs[k][4 * tc];
            float4 bv1 = *(const float4*)&Bs[k][64 + 4 * tc];
            float a[4] = {av.x, av.y, av.z, av.w};
            float b[8] = {bv0.x, bv0.y, bv0.z, bv0.w, bv1.x, bv1.y, bv1.z, bv1.w};
            #pragma unroll
            for (int i = 0; i < 4; i++)
                #pragma unroll
                for (int j = 0; j < 8; j++)
                    acc[i][j] = fmaf(a[i], b[j], acc[i][j]);
        }
    }

    #pragma unroll
    for (int i = 0; i < 4; i++) {
        int r = 4 * tr + i;
        if (r < rows) {
            size_t grow = (size_t)(base + m0 + r) * DH;
            #pragma unroll
            for (int j = 0; j < 8; j++) {
                int cidx = (j < 4) ? (4 * tc + j) : (64 + 4 * tc + (j - 4));
                int col = n0 + cidx;
                float v = acc[i][j] + b1[c * DH + col];
                H1[grow + col] = fmaxf(v, 0.f);
            }
        }
    }
}

__global__ __launch_bounds__(256) void k_gemm2(
    const float* __restrict__ H1, const float* __restrict__ W2, const float* __restrict__ b2,
    const int* __restrict__ offsets, const int* __restrict__ counts,
    float* __restrict__ pooled)
{
    int c = blockIdx.z;
    int cnt = counts[c];
    int m0 = blockIdx.x * MT;
    if (m0 >= cnt) return;
    int rows = min(MT, cnt - m0);
    int n0 = blockIdx.y * NT;
    int base = offsets[c];

    __shared__ float As[KT][MT + 4];
    __shared__ float Bs[KT][NT];
    __shared__ float red[16][NT];

    int t = threadIdx.x;
    int tr = t >> 4;
    int tc = t & 15;
    int lr = t >> 2;
    int lk = (t & 3) * 8;
    const float* arow = (lr < rows) ? (H1 + (size_t)(base + m0 + lr) * DH) : nullptr;

    float acc[4][8];
    #pragma unroll
    for (int i = 0; i < 4; i++)
        #pragma unroll
        for (int j = 0; j < 8; j++) acc[i][j] = 0.f;

    const float* Wp = W2 + (size_t)c * DH * DH + n0;

    for (int k0 = 0; k0 < DH; k0 += KT) {
        __syncthreads();
        if (arow) {
            float4 v0 = *(const float4*)(arow + k0 + lk);
            float4 v1 = *(const float4*)(arow + k0 + lk + 4);
            As[lk + 0][lr] = v0.x; As[lk + 1][lr] = v0.y;
            As[lk + 2][lr] = v0.z; As[lk + 3][lr] = v0.w;
            As[lk + 4][lr] = v1.x; As[lk + 5][lr] = v1.y;
            As[lk + 6][lr] = v1.z; As[lk + 7][lr] = v1.w;
        } else {
            #pragma unroll
            for (int i = 0; i < 8; i++) As[lk + i][lr] = 0.f;
        }
        #pragma unroll
        for (int i = 0; i < 4; i++) {
            int idx = i * 256 + t;
            int kk = idx >> 5;
            int cv = idx & 31;
            *(float4*)&Bs[kk][cv * 4] = *(const float4*)(Wp + (size_t)(k0 + kk) * DH + cv * 4);
        }
        __syncthreads();
        #pragma unroll
        for (int k = 0; k < KT; k++) {
            float4 av  = *(const float4*)&As[k][4 * tr];
            float4 bv0 = *(const float4*)&Bs[k][4 * tc];
            float4 bv1 = *(const float4*)&Bs[k][64 + 4 * tc];
            float a[4] = {av.x, av.y, av.z, av.w};
            float b[8] = {bv0.x, bv0.y, bv0.z, bv0.w, bv1.x, bv1.y, bv1.z, bv1.w};
            #pragma unroll
            for (int i = 0; i < 4; i++)
                #pragma unroll
                for (int j = 0; j < 8; j++)
                    acc[i][j] = fmaf(a[i], b[j], acc[i][j]);
        }
    }

    __syncthreads();
    #pragma unroll
    for (int j = 0; j < 8; j++) {
        int cidx = (j < 4) ? (4 * tc + j) : (64 + 4 * tc + (j - 4));
        float bias = b2[c * DH + n0 + cidx];
        float s = 0.f;
        #pragma unroll
        for (int i = 0; i < 4; i++) {
            if (4 * tr + i < rows) s += fmaxf(acc[i][j] + bias, 0.f);
        }
        red[tr][cidx] = s;
    }
    __syncthreads();
    if (t < NT) {
        float s = 0.f;
        #pragma unroll
        for (int r = 0; r < 16; r++) s += red[r][t];
        atomicAdd(&pooled[c * DH + n0 + t], s);
    }
}

// ---------------- launcher ----------------

extern "C" void kernel_launch(void* const* d_in, const int* in_sizes, int n_in,
                              void* d_out, int out_size, void* d_ws, size_t ws_size,
                              hipStream_t stream) {
    (void)n_in; (void)out_size;
    const float* x    = (const float*)d_in[0];
    const int*   cid  = (const int*)d_in[1];
    const float* W1   = (const float*)d_in[2];
    const float* b1   = (const float*)d_in[3];
    const float* W2   = (const float*)d_in[4];
    const float* b2   = (const float*)d_in[5];
    const float* Wfc  = (const float*)d_in[6];
    const float* bfc  = (const float*)d_in[7];
    const float* Wa   = (const float*)d_in[8];
    const float* ba   = (const float*)d_in[9];
    const float* Wb   = (const float*)d_in[10];
    const float* bb   = (const float*)d_in[11];
    const float* Wc   = (const float*)d_in[12];
    const float* bc   = (const float*)d_in[13];
    const float* Wr   = (const float*)d_in[14];
    const float* br   = (const float*)d_in[15];
    const float* Wcls = (const float*)d_in[16];
    const float* bcls = (const float*)d_in[17];
    float* out = (float*)d_out;
    float* ws  = (float*)d_ws;

    int n = in_sizes[1];

    // ---- fast layout ----
    float* pooled   = ws;                          // 5120 f
    int*   scat_pos = (int*)(ws + 5120);           // 16 i (doubles as counts)
    float* a_logit  = ws + 5136;                   // 16 f
    float* hfc      = ws + 5152;                   // 5120 f -> 10272
    int*   bucket   = (int*)(ws + 10272);          // CNUM * n (padded per-cluster)

    size_t big0 = (((size_t)(10272 + (size_t)CNUM * n) * 4) + 255) & ~(size_t)255;
    size_t w1t_bytes = (size_t)CNUM * DH * DIN * 2;
    size_t w2t_bytes = (size_t)CNUM * DH * DH * 2;
    size_t h1_bytes  = (size_t)CNUM * n * DH * 2;  // padded per-cluster rows
    size_t xb_bytes  = (size_t)n * DIN * 2;
    size_t need = big0 + w1t_bytes + w2t_bytes + h1_bytes + xb_bytes;

    if (ws_size >= need) {
        ushort_t* W1t = (ushort_t*)((char*)d_ws + big0);
        ushort_t* W2t = (ushort_t*)((char*)d_ws + big0 + w1t_bytes);
        ushort_t* H1  = (ushort_t*)((char*)d_ws + big0 + w1t_bytes + w2t_bytes);
        ushort_t* xb  = (ushort_t*)((char*)d_ws + big0 + w1t_bytes + w2t_bytes + h1_bytes);

        int nxb = (n + 3) / 4;
        int nw  = 128 * 2 * CNUM;
        int MAXT = ((n / 128) + CNUM + 1) & ~1;    // even; 88 for n=10000 (div by 8)

        hipMemsetAsync(ws, 0, 5136 * 4, stream);   // pooled + scat_pos
        k_prep<<<1 + NSC + nxb + nw, 256, 0, stream>>>(
            cid, n, bc, x, W1, W2, xb, W1t, W2t, nxb, nw, a_logit, scat_pos, bucket);
        k_g1<<<4 * MAXT, 256, 0, stream>>>(xb, W1t, b1, bucket, scat_pos, n, MAXT, H1);
        k_g2<<<4 * MAXT, 256, 0, stream>>>(H1, W2t, b2, scat_pos, n, MAXT, pooled);
        k_fc2<<<dim3(CNUM, 8), 256, 0, stream>>>(pooled, scat_pos, Wfc, bfc, hfc);
        k_gate2<<<dim3(CNUM, 4), 256, 0, stream>>>(hfc, Wa, ba, Wb, bb, Wc, a_logit);
        k_final<<<1, 1024, 0, stream>>>(hfc, a_logit, Wr, br, Wcls, bcls, out);
    } else {
        // ---- fallback: old fp32 pipeline, old layout ----
        float* pooledF     = ws + 0;
        int*   countsF     = (int*)(ws + 5120);
        int*   offsetsF    = (int*)(ws + 5136);
        float* a_logitF    = ws + 5168;
        int*   scat_posF   = (int*)(ws + 5184);
        float* hfcF        = ws + 5200;
        int*   counts_part = (int*)(ws + 10320);
        int*   bucketF     = (int*)(ws + 11344);

        k_hist<<<NH + 1, 256, 0, stream>>>(cid, n, bc, counts_part, pooledF, a_logitF, scat_posF);
        k_scat_fb<<<NSC, 256, 0, stream>>>(cid, n, counts_part, countsF, offsetsF, scat_posF, bucketF);

        float* H1f = ws + ((11344 + n + 31) & ~31);
        dim3 gg((n + MT - 1) / MT, DH / NT, CNUM);
        k_gemm1<<<gg, 256, 0, stream>>>(x, W1, b1, bucketF, offsetsF, countsF, H1f);
        k_gemm2<<<gg, 256, 0, stream>>>(H1f, W2, b2, offsetsF, countsF, pooledF);

        k_fc2<<<dim3(CNUM, 8), 256, 0, stream>>>(pooledF, countsF, Wfc, bfc, hfcF);
        k_gate2<<<dim3(CNUM, 4), 256, 0, stream>>>(hfcF, Wa, ba, Wb, bb, Wc, a_logitF);
        k_final<<<1, 1024, 0, stream>>>(hfcF, a_logitF, Wr, br, Wcls, bcls, out);
    }
}